// Round 3
// baseline (423.232 us; speedup 1.0000x reference)
//
#include <hip/hip_runtime.h>
#include <hip/hip_bf16.h>

// DirNet: out[k,o,idx[j],d] = SCALE * sum_i x[k,o,idx[j],i] * W[o,d,i] + b[o,d]
// (rows not in image(idx) are a straight copy of x).
// Batched B^T GEMM, bf16 MFMA (16x16x32), fp32 accumulate.
// R3: XCD-swizzled grid (nt-siblings share an XCD L2), double-buffered LDS
//     with register prefetch (1 barrier/iter), nontemporal C stores.

typedef __bf16  bf16x8  __attribute__((ext_vector_type(8)));
typedef float   floatx4 __attribute__((ext_vector_type(4)));

#define O_DIM 18
#define J_DIM 18
#define KB    256
#define C_DIM 512
#define BM    128
#define BN    128
#define BK    32
#define NK    (C_DIM / BK)   // 16 K-iterations
#define LDSS  40   // BK + 8 pad (bf16 elems) -> 80B row stride, 2-way-free b128 reads

__device__ __forceinline__ __bf16 f2bf(float f) { return (__bf16)f; }

__global__ __launch_bounds__(256, 3)
void dirnet_gemm(const float* __restrict__ x, const float* __restrict__ W,
                 const float* __restrict__ bias, const int* __restrict__ idx,
                 float* __restrict__ out)
{
    // ---- XCD-aware decode: ids differing by 8 land on the same XCD (round-robin
    // dispatch). The 4 nt-siblings of one (mt,j,o) A-tile get ids {b, b+8, b+16,
    // b+24} -> same XCD, adjacent in time -> A-tile stays in that XCD's 4MB L2.
    const int id   = blockIdx.x;       // 0..2591
    const int xcd  = id & 7;
    const int slot = id >> 3;          // 0..323
    const int nt   = slot & 3;
    const int g    = (slot >> 2) * 8 + xcd;   // group 0..647
    const int mt   = g & 1;
    const int jo   = g >> 1;           // 0..323
    const int j    = jo % J_DIM;
    const int o    = jo / J_DIM;
    const int jj   = idx[j];

    __shared__ __bf16 As[2][BM * LDSS];
    __shared__ __bf16 Bs[2][BM * LDSS];

    const int tid  = threadIdx.x;
    const int srow = tid >> 2;          // 0..63  (staging row)
    const int scol = (tid & 3) << 3;    // 0,8,16,24 (staging col, elems)

    const size_t xRow0      = ((size_t)((mt * BM + srow) * O_DIM + o) * J_DIM + jj) * C_DIM;
    const size_t xRowStride = (size_t)64 * O_DIM * J_DIM * C_DIM;
    const size_t wRow0      = ((size_t)(o * C_DIM + nt * BN + srow)) * C_DIM;
    const size_t wRowStride = (size_t)64 * C_DIM;

    const int lane = tid & 63;
    const int wv   = tid >> 6;
    const int mOff = (wv & 1) * 64;
    const int nOff = (wv >> 1) * 64;
    const int lrow = lane & 15;         // frag row (A: m, B: n)
    const int lk   = (lane >> 4) << 3;  // frag k offset (quad*8)

    floatx4 acc[4][4] = {};
    float4 pa[2][2], pb[2][2];

    // prologue: issue loads for tile 0
    #pragma unroll
    for (int p = 0; p < 2; ++p) {
        const float* ap = x + xRow0 + (size_t)p * xRowStride + scol;
        pa[p][0] = *(const float4*)ap;
        pa[p][1] = *(const float4*)(ap + 4);
        const float* bp = W + wRow0 + (size_t)p * wRowStride + scol;
        pb[p][0] = *(const float4*)bp;
        pb[p][1] = *(const float4*)(bp + 4);
    }

    for (int t = 0; t < NK; ++t) {
        const int cur = t & 1;

        // convert prefetched tile -> LDS stage[cur]
        #pragma unroll
        for (int p = 0; p < 2; ++p) {
            bf16x8 sa;
            sa[0]=f2bf(pa[p][0].x); sa[1]=f2bf(pa[p][0].y);
            sa[2]=f2bf(pa[p][0].z); sa[3]=f2bf(pa[p][0].w);
            sa[4]=f2bf(pa[p][1].x); sa[5]=f2bf(pa[p][1].y);
            sa[6]=f2bf(pa[p][1].z); sa[7]=f2bf(pa[p][1].w);
            *(bf16x8*)&As[cur][(p * 64 + srow) * LDSS + scol] = sa;

            bf16x8 sb;
            sb[0]=f2bf(pb[p][0].x); sb[1]=f2bf(pb[p][0].y);
            sb[2]=f2bf(pb[p][0].z); sb[3]=f2bf(pb[p][0].w);
            sb[4]=f2bf(pb[p][1].x); sb[5]=f2bf(pb[p][1].y);
            sb[6]=f2bf(pb[p][1].z); sb[7]=f2bf(pb[p][1].w);
            *(bf16x8*)&Bs[cur][(p * 64 + srow) * LDSS + scol] = sb;
        }

        __syncthreads();   // writes of stage[cur] visible; prior reads of stage[cur] done

        // issue loads for tile t+1 AFTER the barrier so its vmcnt(0) drain
        // never waits on them; consumed at next iteration's cvt.
        if (t + 1 < NK) {
            const int k0 = (t + 1) * BK;
            #pragma unroll
            for (int p = 0; p < 2; ++p) {
                const float* ap = x + xRow0 + (size_t)p * xRowStride + k0 + scol;
                pa[p][0] = *(const float4*)ap;
                pa[p][1] = *(const float4*)(ap + 4);
                const float* bp = W + wRow0 + (size_t)p * wRowStride + k0 + scol;
                pb[p][0] = *(const float4*)bp;
                pb[p][1] = *(const float4*)(bp + 4);
            }
        }

        bf16x8 af[4], bfr[4];
        #pragma unroll
        for (int mi = 0; mi < 4; ++mi)
            af[mi] = *(const bf16x8*)&As[cur][(mOff + mi * 16 + lrow) * LDSS + lk];
        #pragma unroll
        for (int ni = 0; ni < 4; ++ni)
            bfr[ni] = *(const bf16x8*)&Bs[cur][(nOff + ni * 16 + lrow) * LDSS + lk];

        #pragma unroll
        for (int mi = 0; mi < 4; ++mi)
            #pragma unroll
            for (int ni = 0; ni < 4; ++ni)
                acc[mi][ni] = __builtin_amdgcn_mfma_f32_16x16x32_bf16(
                    af[mi], bfr[ni], acc[mi][ni], 0, 0, 0);
    }

    // Epilogue: C/D layout col = lane&15 (n), row = (lane>>4)*4 + r (m).
    // Nontemporal stores: don't let the 172MB write stream evict x from L2/L3.
    const float scale = 0.04419417382415922f;  // 1/sqrt(512), LR_MUL = 1
    const int rbase = (lane >> 4) << 2;
    #pragma unroll
    for (int ni = 0; ni < 4; ++ni) {
        const int d  = nt * BN + nOff + ni * 16 + lrow;
        const float bv = bias[o * C_DIM + d];
        #pragma unroll
        for (int mi = 0; mi < 4; ++mi) {
            #pragma unroll
            for (int r = 0; r < 4; ++r) {
                const int kr = mt * BM + mOff + mi * 16 + rbase + r;
                __builtin_nontemporal_store(
                    acc[mi][ni][r] * scale + bv,
                    &out[((size_t)(kr * O_DIM + o) * J_DIM + jj) * C_DIM + d]);
            }
        }
    }
}

// Rows jj not present in idx keep their x values. With idx = arange(18) this
// kernel does no memory traffic (membership always true -> early exit).
__global__ void copy_nonsel(const float* __restrict__ x, const int* __restrict__ idx,
                            float* __restrict__ out)
{
    const int jj = blockIdx.x;
    const int o  = blockIdx.y;
    bool member = false;
    for (int t = 0; t < J_DIM; ++t) member = member || (idx[t] == jj);
    if (member) return;
    const int tid = threadIdx.x;
    for (int k = 0; k < KB; ++k) {
        const size_t base = ((size_t)(k * O_DIM + o) * J_DIM + jj) * C_DIM;
        for (int c = tid * 4; c < C_DIM; c += 256 * 4) {
            *(float4*)&out[base + c] = *(const float4*)&x[base + c];
        }
    }
}

extern "C" void kernel_launch(void* const* d_in, const int* in_sizes, int n_in,
                              void* d_out, int out_size, void* d_ws, size_t ws_size,
                              hipStream_t stream) {
    const float* x   = (const float*)d_in[0];
    const float* W   = (const float*)d_in[1];
    const float* b   = (const float*)d_in[2];
    const int*   idx = (const int*)d_in[3];
    float* out = (float*)d_out;

    dirnet_gemm<<<dim3(8 * J_DIM * O_DIM), 256, 0, stream>>>(x, W, b, idx, out);
    copy_nonsel<<<dim3(J_DIM, O_DIM), 256, 0, stream>>>(x, idx, out);
}

// Round 5
// 407.679 us; speedup vs baseline: 1.0382x; 1.0382x over previous
//
#include <hip/hip_runtime.h>
#include <hip/hip_bf16.h>

// DirNet: out[k,o,idx[j],d] = SCALE * sum_i x[k,o,idx[j],i] * W[o,d,i] + b[o,d]
// (rows not in image(idx) are a straight copy of x).
// Batched B^T GEMM, bf16 MFMA (16x16x32), fp32 accumulate.
// R5: R4 design with the grid-size bug fixed (2592 -> 5184 blocks; R4 left
//     half the (j,o) slices uncomputed). 512-thread blocks, 8 waves x (32x32)
//     per 128x64 tile, ~75 VGPR -> target 3 blocks/CU = 24 waves/CU.
//     Single-buffer LDS (15KB), register prefetch crossing no barriers,
//     XCD swizzle (R3-proven: FETCH 357->165MB).

typedef __bf16  bf16x8  __attribute__((ext_vector_type(8)));
typedef __bf16  bf16x4  __attribute__((ext_vector_type(4)));
typedef float   floatx4 __attribute__((ext_vector_type(4)));

#define O_DIM 18
#define J_DIM 18
#define KB    256
#define C_DIM 512
#define BM    128
#define BN    64
#define BK    32
#define NK    (C_DIM / BK)   // 16 K-iterations
#define LDSS  40             // BK + 8 pad -> 80B row stride, 2-way-free b128 reads

__device__ __forceinline__ __bf16 f2bf(float f) { return (__bf16)f; }

__global__ __launch_bounds__(512, 6)
void dirnet_gemm(const float* __restrict__ x, const float* __restrict__ W,
                 const float* __restrict__ bias, const int* __restrict__ idx,
                 float* __restrict__ out)
{
    // XCD-aware decode: id = s2*64 + nt*8 + xcd. The 8 nt-siblings sharing one
    // A-tile (mt,j,o) differ by 8 in id -> same XCD (round-robin dispatch),
    // adjacent in time -> 256KB A-tile served from that XCD's 4MB L2.
    const int id   = blockIdx.x;       // 0..5183
    const int xcd  = id & 7;
    const int slot = id >> 3;          // 0..647
    const int nt   = slot & 7;         // 8 N-tiles of 64
    const int g    = (slot >> 3) * 8 + xcd;   // 0..647
    const int mt   = g & 1;            // 2 M-tiles of 128
    const int jo   = g >> 1;           // 0..323
    const int j    = jo % J_DIM;
    const int o    = jo / J_DIM;
    const int jj   = idx[j];

    __shared__ __bf16 As[BM * LDSS];   // 10240 B
    __shared__ __bf16 Bs[BN * LDSS];   //  5120 B

    const int tid  = threadIdx.x;
    // staging: A 128x32 fp32 (8 floats/thread), B 64x32 fp32 (4 floats/thread)
    const int arow = tid >> 2;          // 0..127
    const int acol = (tid & 3) << 3;    // 0,8,16,24
    const int brow = tid >> 3;          // 0..63
    const int bcol = (tid & 7) << 2;    // 0,4,...,28

    const float* xp = x + ((size_t)((mt * BM + arow) * O_DIM + o) * J_DIM + jj) * C_DIM + acol;
    const float* wp = W + ((size_t)(o * C_DIM + nt * BN + brow)) * C_DIM + bcol;

    const int lane = tid & 63;
    const int wv   = tid >> 6;          // 0..7
    const int mOff = (wv & 3) * 32;     // 4 m-strips of 32
    const int nOff = (wv >> 2) * 32;    // 2 n-strips of 32
    const int lrow = lane & 15;         // frag row (A: m, B: n)
    const int lk   = (lane >> 4) << 3;  // frag k offset (quad*8)

    floatx4 acc[2][2] = {};
    float4 pa0, pa1, pb;

    // prologue: loads for tile 0
    pa0 = *(const float4*)(xp);
    pa1 = *(const float4*)(xp + 4);
    pb  = *(const float4*)(wp);

    for (int t = 0; t < NK; ++t) {
        // convert prefetched tile (no barrier between its load and this use)
        bf16x8 sa;
        sa[0]=f2bf(pa0.x); sa[1]=f2bf(pa0.y); sa[2]=f2bf(pa0.z); sa[3]=f2bf(pa0.w);
        sa[4]=f2bf(pa1.x); sa[5]=f2bf(pa1.y); sa[6]=f2bf(pa1.z); sa[7]=f2bf(pa1.w);
        bf16x4 sb;
        sb[0]=f2bf(pb.x); sb[1]=f2bf(pb.y); sb[2]=f2bf(pb.z); sb[3]=f2bf(pb.w);

        __syncthreads();   // prior iteration's frag reads complete
        *(bf16x8*)&As[arow * LDSS + acol] = sa;
        *(bf16x4*)&Bs[brow * LDSS + bcol] = sb;
        __syncthreads();   // staged tile visible

        // prefetch tile t+1: issued here, consumed at top of t+1 -> crosses no
        // barrier, so the barrier's waitcnt drain never touches these loads.
        if (t + 1 < NK) {
            const int k0 = (t + 1) * BK;
            pa0 = *(const float4*)(xp + k0);
            pa1 = *(const float4*)(xp + k0 + 4);
            pb  = *(const float4*)(wp + k0);
        }

        bf16x8 af[2], bfr[2];
        #pragma unroll
        for (int mi = 0; mi < 2; ++mi)
            af[mi] = *(const bf16x8*)&As[(mOff + mi * 16 + lrow) * LDSS + lk];
        #pragma unroll
        for (int ni = 0; ni < 2; ++ni)
            bfr[ni] = *(const bf16x8*)&Bs[(nOff + ni * 16 + lrow) * LDSS + lk];

        #pragma unroll
        for (int mi = 0; mi < 2; ++mi)
            #pragma unroll
            for (int ni = 0; ni < 2; ++ni)
                acc[mi][ni] = __builtin_amdgcn_mfma_f32_16x16x32_bf16(
                    af[mi], bfr[ni], acc[mi][ni], 0, 0, 0);
    }

    // Epilogue: C/D layout col = lane&15 (n), row = (lane>>4)*4 + r (m)
    const float scale = 0.04419417382415922f;  // 1/sqrt(512), LR_MUL = 1
    const int rbase = (lane >> 4) << 2;
    #pragma unroll
    for (int ni = 0; ni < 2; ++ni) {
        const int d  = nt * BN + nOff + ni * 16 + lrow;
        const float bv = bias[o * C_DIM + d];
        #pragma unroll
        for (int mi = 0; mi < 2; ++mi) {
            #pragma unroll
            for (int r = 0; r < 4; ++r) {
                const int kr = mt * BM + mOff + mi * 16 + rbase + r;
                out[((size_t)(kr * O_DIM + o) * J_DIM + jj) * C_DIM + d] =
                    acc[mi][ni][r] * scale + bv;
            }
        }
    }
}

// Rows jj not present in idx keep their x values. With idx = arange(18) this
// kernel does no memory traffic (membership always true -> early exit).
__global__ void copy_nonsel(const float* __restrict__ x, const int* __restrict__ idx,
                            float* __restrict__ out)
{
    const int jj = blockIdx.x;
    const int o  = blockIdx.y;
    bool member = false;
    for (int t = 0; t < J_DIM; ++t) member = member || (idx[t] == jj);
    if (member) return;
    const int tid = threadIdx.x;
    for (int k = 0; k < KB; ++k) {
        const size_t base = ((size_t)(k * O_DIM + o) * J_DIM + jj) * C_DIM;
        for (int c = tid * 4; c < C_DIM; c += 256 * 4) {
            *(float4*)&out[base + c] = *(const float4*)&x[base + c];
        }
    }
}

extern "C" void kernel_launch(void* const* d_in, const int* in_sizes, int n_in,
                              void* d_out, int out_size, void* d_ws, size_t ws_size,
                              hipStream_t stream) {
    const float* x   = (const float*)d_in[0];
    const float* W   = (const float*)d_in[1];
    const float* b   = (const float*)d_in[2];
    const int*   idx = (const int*)d_in[3];
    float* out = (float*)d_out;

    // 2 mt * 8 nt * 18 j * 18 o = 5184 blocks (R4 bug: launched only 2592)
    dirnet_gemm<<<dim3(2 * 8 * J_DIM * O_DIM), 512, 0, stream>>>(x, W, b, idx, out);
    copy_nonsel<<<dim3(J_DIM, O_DIM), 256, 0, stream>>>(x, idx, out);
}

// Round 6
// 367.630 us; speedup vs baseline: 1.1512x; 1.1089x over previous
//
#include <hip/hip_runtime.h>
#include <hip/hip_bf16.h>

// DirNet: out[k,o,idx[j],d] = SCALE * sum_i x[k,o,idx[j],i] * W[o,d,i] + b[o,d]
// Batched B^T GEMM, bf16 MFMA (16x16x32), fp32 accumulate.
// R6: latency attack. Fat tile back (128x128, 4 waves, 16 MFMA/iter/wave —
//     R2's shape pulled 3 TB/s vs R5's 1.7), depth-2 A / depth-1 B register
//     prefetch, and RELAXED barriers (lgkmcnt-only) so prefetch loads stay in
//     flight across s_barrier (HIP __syncthreads drains vmcnt(0) — m97).
//     XCD swizzle kept (R3-proven: FETCH 357->165MB).

typedef __bf16  bf16x8  __attribute__((ext_vector_type(8)));
typedef float   floatx4 __attribute__((ext_vector_type(4)));

#define O_DIM 18
#define J_DIM 18
#define KB    256
#define C_DIM 512
#define BM    128
#define BN    128
#define BK    32
#define NK    (C_DIM / BK)   // 16 K-iterations
#define LDSS  40             // BK + 8 pad -> 80B stride, 2-way-free b128 reads

__device__ __forceinline__ __bf16 f2bf(float f) { return (__bf16)f; }

// Barrier that waits only LDS ops (lgkmcnt(0)), leaving global loads (vmcnt)
// in flight. 0xc07f = vmcnt 63 | expcnt 7 | lgkmcnt 0 (gfx9 encoding).
__device__ __forceinline__ void barrier_lds() {
    __builtin_amdgcn_s_waitcnt(0xc07f);
    __builtin_amdgcn_s_barrier();
}

__global__ __launch_bounds__(256, 2)
void dirnet_gemm(const float* __restrict__ x, const float* __restrict__ W,
                 const float* __restrict__ bias, const int* __restrict__ idx,
                 float* __restrict__ out)
{
    // XCD-aware decode: the 4 nt-siblings of one A-tile differ by 8 in id ->
    // same XCD (round-robin dispatch) -> A-tile served from that XCD's L2.
    const int id   = blockIdx.x;       // 0..2591
    const int xcd  = id & 7;
    const int slot = id >> 3;          // 0..323
    const int nt   = slot & 3;
    const int g    = (slot >> 2) * 8 + xcd;   // 0..647
    const int mt   = g & 1;
    const int jo   = g >> 1;           // 0..323
    const int j    = jo % J_DIM;
    const int o    = jo / J_DIM;
    const int jj   = idx[j];

    __shared__ __bf16 As[BM * LDSS];   // 10240 B
    __shared__ __bf16 Bs[BN * LDSS];   // 10240 B

    const int tid  = threadIdx.x;
    const int srow = tid >> 2;          // 0..63
    const int scol = (tid & 3) << 3;    // 0,8,16,24

    const float* xp = x + ((size_t)((mt * BM + srow) * O_DIM + o) * J_DIM + jj) * C_DIM + scol;
    const size_t xRS = (size_t)64 * O_DIM * J_DIM * C_DIM;
    const float* wp = W + ((size_t)(o * C_DIM + nt * BN + srow)) * C_DIM + scol;
    const size_t wRS = (size_t)64 * C_DIM;

    const int lane = tid & 63;
    const int wv   = tid >> 6;
    const int mOff = (wv & 1) * 64;
    const int nOff = (wv >> 1) * 64;
    const int lrow = lane & 15;         // frag row (A: m, B: n)
    const int lk   = (lane >> 4) << 3;  // frag k offset (quad*8)

    floatx4 acc[4][4] = {};
    float4 pa[2][2][2];   // [set][row-half][float4-half]  A: depth-2
    float4 pb[2][2];      // [row-half][float4-half]       B: depth-1

    // Prologue. FIFO order = consume order: B(0), A(0), A(1).
    #pragma unroll
    for (int p = 0; p < 2; ++p) {
        pb[p][0] = *(const float4*)(wp + p * wRS);
        pb[p][1] = *(const float4*)(wp + p * wRS + 4);
    }
    #pragma unroll
    for (int p = 0; p < 2; ++p) {
        pa[0][p][0] = *(const float4*)(xp + p * xRS);
        pa[0][p][1] = *(const float4*)(xp + p * xRS + 4);
    }
    #pragma unroll
    for (int p = 0; p < 2; ++p) {
        pa[1][p][0] = *(const float4*)(xp + p * xRS + BK);
        pa[1][p][1] = *(const float4*)(xp + p * xRS + BK + 4);
    }

    #pragma unroll
    for (int t = 0; t < NK; ++t) {
        const int s = t & 1;

        // Convert tile t: A prefetched 2 iters ago, B 1 iter ago.
        // Consume A first (older in FIFO), then B — waits never drain the
        // younger in-flight prefetches.
        bf16x8 sa[2], sb[2];
        #pragma unroll
        for (int p = 0; p < 2; ++p) {
            sa[p][0]=f2bf(pa[s][p][0].x); sa[p][1]=f2bf(pa[s][p][0].y);
            sa[p][2]=f2bf(pa[s][p][0].z); sa[p][3]=f2bf(pa[s][p][0].w);
            sa[p][4]=f2bf(pa[s][p][1].x); sa[p][5]=f2bf(pa[s][p][1].y);
            sa[p][6]=f2bf(pa[s][p][1].z); sa[p][7]=f2bf(pa[s][p][1].w);
        }
        #pragma unroll
        for (int p = 0; p < 2; ++p) {
            sb[p][0]=f2bf(pb[p][0].x); sb[p][1]=f2bf(pb[p][0].y);
            sb[p][2]=f2bf(pb[p][0].z); sb[p][3]=f2bf(pb[p][0].w);
            sb[p][4]=f2bf(pb[p][1].x); sb[p][5]=f2bf(pb[p][1].y);
            sb[p][6]=f2bf(pb[p][1].z); sb[p][7]=f2bf(pb[p][1].w);
        }

        barrier_lds();   // all waves' prior frag ds_reads retired (lgkmcnt 0)
        #pragma unroll
        for (int p = 0; p < 2; ++p) {
            *(bf16x8*)&As[(p * 64 + srow) * LDSS + scol] = sa[p];
            *(bf16x8*)&Bs[(p * 64 + srow) * LDSS + scol] = sb[p];
        }
        barrier_lds();   // staged tile visible; vmcnt prefetches NOT drained

        // Refill: B for t+1 first, A for t+2 second (FIFO = next consume order)
        if (t + 1 < NK) {
            const int k1 = (t + 1) * BK;
            #pragma unroll
            for (int p = 0; p < 2; ++p) {
                pb[p][0] = *(const float4*)(wp + p * wRS + k1);
                pb[p][1] = *(const float4*)(wp + p * wRS + k1 + 4);
            }
        }
        if (t + 2 < NK) {
            const int k2 = (t + 2) * BK;
            #pragma unroll
            for (int p = 0; p < 2; ++p) {
                pa[s][p][0] = *(const float4*)(xp + p * xRS + k2);
                pa[s][p][1] = *(const float4*)(xp + p * xRS + k2 + 4);
            }
        }

        bf16x8 af[4], bfr[4];
        #pragma unroll
        for (int mi = 0; mi < 4; ++mi)
            af[mi] = *(const bf16x8*)&As[(mOff + mi * 16 + lrow) * LDSS + lk];
        #pragma unroll
        for (int ni = 0; ni < 4; ++ni)
            bfr[ni] = *(const bf16x8*)&Bs[(nOff + ni * 16 + lrow) * LDSS + lk];

        #pragma unroll
        for (int mi = 0; mi < 4; ++mi)
            #pragma unroll
            for (int ni = 0; ni < 4; ++ni)
                acc[mi][ni] = __builtin_amdgcn_mfma_f32_16x16x32_bf16(
                    af[mi], bfr[ni], acc[mi][ni], 0, 0, 0);
    }

    // Epilogue: C/D layout col = lane&15 (n), row = (lane>>4)*4 + r (m)
    const float scale = 0.04419417382415922f;  // 1/sqrt(512), LR_MUL = 1
    const int rbase = (lane >> 4) << 2;
    #pragma unroll
    for (int ni = 0; ni < 4; ++ni) {
        const int d  = nt * BN + nOff + ni * 16 + lrow;
        const float bv = bias[o * C_DIM + d];
        #pragma unroll
        for (int mi = 0; mi < 4; ++mi) {
            #pragma unroll
            for (int r = 0; r < 4; ++r) {
                const int kr = mt * BM + mOff + mi * 16 + rbase + r;
                out[((size_t)(kr * O_DIM + o) * J_DIM + jj) * C_DIM + d] =
                    acc[mi][ni][r] * scale + bv;
            }
        }
    }
}

// Rows jj not present in idx keep their x values. With idx = arange(18) this
// kernel does no memory traffic (membership always true -> early exit).
__global__ void copy_nonsel(const float* __restrict__ x, const int* __restrict__ idx,
                            float* __restrict__ out)
{
    const int jj = blockIdx.x;
    const int o  = blockIdx.y;
    bool member = false;
    for (int t = 0; t < J_DIM; ++t) member = member || (idx[t] == jj);
    if (member) return;
    const int tid = threadIdx.x;
    for (int k = 0; k < KB; ++k) {
        const size_t base = ((size_t)(k * O_DIM + o) * J_DIM + jj) * C_DIM;
        for (int c = tid * 4; c < C_DIM; c += 256 * 4) {
            *(float4*)&out[base + c] = *(const float4*)&x[base + c];
        }
    }
}

extern "C" void kernel_launch(void* const* d_in, const int* in_sizes, int n_in,
                              void* d_out, int out_size, void* d_ws, size_t ws_size,
                              hipStream_t stream) {
    const float* x   = (const float*)d_in[0];
    const float* W   = (const float*)d_in[1];
    const float* b   = (const float*)d_in[2];
    const int*   idx = (const int*)d_in[3];
    float* out = (float*)d_out;

    // 2 mt * 4 nt * 18 j * 18 o = 2592 blocks
    dirnet_gemm<<<dim3(2 * 4 * J_DIM * O_DIM), 256, 0, stream>>>(x, W, b, idx, out);
    copy_nonsel<<<dim3(J_DIM, O_DIM), 256, 0, stream>>>(x, idx, out);
}